// Round 1
// 216.859 us; speedup vs baseline: 1.1862x; 1.1862x over previous
//
#include <hip/hip_runtime.h>
#include <stdint.h>

#define N_NODES 4096
#define F_DIM   256
#define BATCH   8

typedef __attribute__((ext_vector_type(8))) __bf16 bf16x8;
typedef __attribute__((ext_vector_type(4))) float  f32x4;
typedef __attribute__((ext_vector_type(8))) unsigned short u16x8;

typedef const __attribute__((address_space(1))) void* gas1_t;
typedef __attribute__((address_space(3))) void*       las3_t;

__device__ __forceinline__ void stage16(const void* g, void* l) {
  __builtin_amdgcn_global_load_lds((gas1_t)g, (las3_t)l, 16, 0, 0);
}

__device__ __forceinline__ unsigned short f2bf(float f) {
  union { float f; uint32_t u; } v; v.f = f;
  uint32_t u = v.u;
  return (unsigned short)((u + 0x7FFFu + ((u >> 16) & 1u)) >> 16); // RTNE
}
__device__ __forceinline__ float bf2f(unsigned short u) {
  union { uint32_t u; float f; } v; v.u = ((uint32_t)u) << 16;
  return v.f;
}

// ---------------- k_pre: fused H/W bf16 casts + symmetrize+degree ----------------
__global__ __launch_bounds__(256) void k_pre(const float* __restrict__ A,
                                             unsigned short* __restrict__ Sb,
                                             float* __restrict__ D,
                                             const float4* __restrict__ H4,
                                             ushort4* __restrict__ Hb4,
                                             const float* __restrict__ W,
                                             unsigned short* __restrict__ Wt) {
  int t = threadIdx.x;
  int bid = blockIdx.y * 64 + blockIdx.x;
  {
    int i = bid * 512 + t;
    float4 v = H4[i];
    ushort4 o; o.x = f2bf(v.x); o.y = f2bf(v.y); o.z = f2bf(v.z); o.w = f2bf(v.w);
    Hb4[i] = o;
    i += 256;
    v = H4[i];
    o.x = f2bf(v.x); o.y = f2bf(v.y); o.z = f2bf(v.z); o.w = f2bf(v.w);
    Hb4[i] = o;
  }
  if (bid < 256) Wt[t * 256 + bid] = f2bf(W[bid * 256 + t]);

  int bi = blockIdx.y, bj = blockIdx.x;
  if (bj < bi) return;
  __shared__ float L1[64][65];
  __shared__ float L2[64][65];
  __shared__ float Pr[4][64];
  __shared__ float Pc[4][64];
  int i0 = bi * 64, j0 = bj * 64;
  for (int it = 0; it < 16; ++it) {
    int idx = it * 256 + t;
    int r = idx >> 6, c = idx & 63;
    L1[r][c] = A[(size_t)(i0 + r) * N_NODES + (j0 + c)];
    L2[c][r] = A[(size_t)(j0 + r) * N_NODES + (i0 + c)];
  }
  __syncthreads();
  float colsum = 0.f;
  int cfix = t & 63, q = t >> 6;
  for (int it = 0; it < 16; ++it) {
    int r = it * 4 + q;
    float v = 0.5f * (L1[r][cfix] + L2[r][cfix]);
    v = v > 0.f ? v : 0.f;
    Sb[(size_t)(i0 + r) * N_NODES + (j0 + cfix)] = f2bf(v);
    colsum += v;
    L1[r][cfix] = v;
  }
  Pc[q][cfix] = colsum;
  __syncthreads();
  {
    int r = t & 63, seg = t >> 6;
    float s = 0.f;
    for (int c = seg * 16; c < seg * 16 + 16; ++c) s += L1[r][c];
    Pr[seg][r] = s;
  }
  __syncthreads();
  if (t < 64) {
    float d = Pr[0][t] + Pr[1][t] + Pr[2][t] + Pr[3][t];
    atomicAdd(&D[i0 + t], d);
  } else if (t < 128 && bi != bj) {
    int c = t - 64;
    float d = Pc[0][c] + Pc[1][c] + Pc[2][c] + Pc[3][c];
    atomicAdd(&D[j0 + c], d);
  }
  if (bi != bj) {
    for (int it = 0; it < 16; ++it) {
      int idx = it * 256 + t;
      int ro = idx >> 6, co = idx & 63;
      Sb[(size_t)(j0 + ro) * N_NODES + (i0 + co)] = f2bf(L1[co][ro]);
    }
  }
}

__global__ void k_dinv(const float* __restrict__ D, float* __restrict__ dinv) {
  int i = blockIdx.x * blockDim.x + threadIdx.x;
  if (i < N_NODES) {
    float d = D[i];
    dinv[i] = d > 0.f ? 1.0f / sqrtf(d) : 0.f;
  }
}

// ---------------- GEMM1: HW = Hb @ Wt^T; HWb (bf16) + Gt[b*256+o][n]=dinv[n]*HW ----
__global__ __launch_bounds__(256) void k_gemm1(const unsigned short* __restrict__ Hb,
                                               const unsigned short* __restrict__ Wt,
                                               const float* __restrict__ dinv,
                                               unsigned short* __restrict__ HWb,
                                               unsigned short* __restrict__ Gt) {
  __shared__ __align__(16) unsigned short As[128 * 32];
  __shared__ __align__(16) unsigned short Bs[128 * 32];
  __shared__ __align__(16) unsigned short T[128][136];
  int t = threadIdx.x;
  int lane = t & 63;
  int q = lane >> 4, r16 = lane & 15;
  int wave = t >> 6;
  int wm = wave >> 1, wn = wave & 1;
  int m0 = blockIdx.y * 128;
  int o0 = blockIdx.x * 128;
  const int K = 256;

  const unsigned short* Abase = Hb + (size_t)m0 * K;
  const unsigned short* Bbase = Wt + (size_t)o0 * K;

  f32x4 acc[4][4];
#pragma unroll
  for (int i = 0; i < 4; ++i)
#pragma unroll
    for (int j = 0; j < 4; ++j) acc[i][j] = f32x4{0.f, 0.f, 0.f, 0.f};

  int idx0 = t, idx1 = 256 + t;
  int wb0 = (t & ~63) * 8;
  int wb1 = (256 + (t & ~63)) * 8;

  for (int kt = 0; kt < K / 32; ++kt) {
    int kof = kt * 32;
    stage16(Abase + (size_t)(idx0 >> 2) * K + kof + ((idx0 & 3) << 3), &As[wb0]);
    stage16(Abase + (size_t)(idx1 >> 2) * K + kof + ((idx1 & 3) << 3), &As[wb1]);
    stage16(Bbase + (size_t)(idx0 >> 2) * K + kof + ((idx0 & 3) << 3), &Bs[wb0]);
    stage16(Bbase + (size_t)(idx1 >> 2) * K + kof + ((idx1 & 3) << 3), &Bs[wb1]);
    __syncthreads();
    bf16x8 a[4], b[4];
#pragma unroll
    for (int mi = 0; mi < 4; ++mi)
      a[mi] = *(const bf16x8*)&As[(wm * 64 + mi * 16 + r16) * 32 + q * 8];
#pragma unroll
    for (int ni = 0; ni < 4; ++ni)
      b[ni] = *(const bf16x8*)&Bs[(wn * 64 + ni * 16 + r16) * 32 + q * 8];
#pragma unroll
    for (int mi = 0; mi < 4; ++mi)
#pragma unroll
      for (int ni = 0; ni < 4; ++ni)
        acc[mi][ni] = __builtin_amdgcn_mfma_f32_16x16x32_bf16(a[mi], b[ni], acc[mi][ni], 0, 0, 0);
    __syncthreads();
  }

#pragma unroll
  for (int mi = 0; mi < 4; ++mi) {
    int row = wm * 64 + mi * 16 + q * 4;
#pragma unroll
    for (int ni = 0; ni < 4; ++ni) {
      int col = wn * 64 + ni * 16 + r16;
#pragma unroll
      for (int rr = 0; rr < 4; ++rr) {
        unsigned short h = f2bf(acc[mi][ni][rr]);
        HWb[(size_t)(m0 + row + rr) * F_DIM + (o0 + col)] = h;
        T[col][row + rr] = h;
      }
    }
  }
  __syncthreads();
  int b = m0 >> 12, n0 = m0 & 4095;
  for (int it = 0; it < 8; ++it) {
    int unit = it * 256 + t;
    int ro = unit >> 4;
    int cs = (unit & 15) * 8;
    u16x8 v = *(const u16x8*)&T[ro][cs];
    u16x8 w;
#pragma unroll
    for (int j = 0; j < 8; ++j)
      w[j] = f2bf(bf2f(v[j]) * dinv[n0 + cs + j]);
    *(u16x8*)&Gt[(size_t)(b * 256 + o0 + ro) * N_NODES + n0 + cs] = w;
  }
}

// ---------------- GEMM2: triple-buffered counted-vmcnt pipeline ----------------
// BM=256 x BN=128, 8 waves (4M x 2N), per-wave 64x64, BK=64, K=4096.
// LDS: 3 buffers x (A 32KB + B 16KB) = 144 KB -> 1 block/CU, grid 256 = 1/CU.
// T2: chunk ^= (row&7) XOR swizzle, applied as pre-swizzled GLOBAL source for
//     global_load_lds (linear LDS dest) + swizzled ds_read offsets.
// T4: one s_barrier + s_waitcnt vmcnt(6) per K-tile; 12 loads in flight; never
//     drain to 0 in the main loop (stage target is 2 tiles ahead -> always a
//     buffer whose readers retired before the previous barrier).
// T5: setprio(1) around the MFMA cluster.
#define LDSB 49152  // bytes per buffer: A 32768 + B 16384

__global__ __launch_bounds__(512, 2) void k_gemm2(const unsigned short* __restrict__ Sb,
                                                  const unsigned short* __restrict__ Gt,
                                                  const unsigned short* __restrict__ HWb,
                                                  const float* __restrict__ dinv,
                                                  float* __restrict__ Out) {
  __shared__ __align__(16) unsigned short LDS[3 * 24576];  // 147456 B
  const int NT = N_NODES / 64;  // 64 K-tiles
  int t = threadIdx.x;
  int lane = t & 63, r16 = lane & 15, q = lane >> 4;
  int wave = t >> 6;
  int wm = wave >> 1, wn = wave & 1;

  // XCD patch swizzle: 256 blocks, bid%8 -> XCD; each XCD owns a 4x8 tile patch.
  int bid = blockIdx.x;
  int xcd = bid & 7, j = bid >> 3;          // j in 0..31
  int mt = (xcd >> 1) * 4 + (j & 3);        // 0..15
  int nt = (xcd & 1) * 8 + (j >> 2);        // 0..15
  int m0 = mt * 256, n0 = nt * 128;

  // staging: per K-tile 6 x global_load_lds per thread (A:4, B:2).
  // slot s = i*512 + t; row = s>>3; store chunk c = (s&7) ^ (row&7) at slot.
  const char* aSrc[4]; const char* bSrc[2];
  uint32_t aDst[4], bDst[2];
#pragma unroll
  for (int i = 0; i < 4; ++i) {
    int slot = i * 512 + t;
    int row = slot >> 3;
    int c = (slot & 7) ^ (row & 7);
    aSrc[i] = (const char*)Sb + (size_t)(m0 + row) * 8192 + c * 16;
    aDst[i] = (uint32_t)(i * 512 + (t & ~63)) * 16;
  }
#pragma unroll
  for (int i = 0; i < 2; ++i) {
    int slot = i * 512 + t;
    int row = slot >> 3;
    int c = (slot & 7) ^ (row & 7);
    bSrc[i] = (const char*)Gt + (size_t)(n0 + row) * 8192 + c * 16;
    bDst[i] = 32768u + (uint32_t)(i * 512 + (t & ~63)) * 16;
  }

  // ds_read byte offsets (within a buffer), swizzle-matched.
  int aoff[4][2], boff[4][2];
#pragma unroll
  for (int mi = 0; mi < 4; ++mi) {
    int ra = wm * 64 + mi * 16 + r16;
#pragma unroll
    for (int ks = 0; ks < 2; ++ks)
      aoff[mi][ks] = ra * 128 + (((ks * 4 + q) ^ (ra & 7)) << 4);
  }
#pragma unroll
  for (int ni = 0; ni < 4; ++ni) {
    int rb = wn * 64 + ni * 16 + r16;
#pragma unroll
    for (int ks = 0; ks < 2; ++ks)
      boff[ni][ks] = 32768 + rb * 128 + (((ks * 4 + q) ^ (rb & 7)) << 4);
  }

  f32x4 acc[4][4];
#pragma unroll
  for (int i = 0; i < 4; ++i)
#pragma unroll
    for (int jj = 0; jj < 4; ++jj) acc[i][jj] = f32x4{0.f, 0.f, 0.f, 0.f};

  auto stage_tile = [&](int kt2, uint32_t bufByte) {
    size_t kb = (size_t)kt2 * 128;
#pragma unroll
    for (int i = 0; i < 4; ++i)
      stage16(aSrc[i] + kb, (char*)LDS + bufByte + aDst[i]);
#pragma unroll
    for (int i = 0; i < 2; ++i)
      stage16(bSrc[i] + kb, (char*)LDS + bufByte + bDst[i]);
  };

  // tile body: mode 2 = stage kt+2 & vmcnt(6); mode 1 = vmcnt(0); mode 0 = last.
  auto tile_body = [&](int kt, uint32_t cur, int mode) {
    bf16x8 aR[4][2], bR[4][2];
#pragma unroll
    for (int mi = 0; mi < 4; ++mi)
#pragma unroll
      for (int ks = 0; ks < 2; ++ks)
        aR[mi][ks] = *(const bf16x8*)((const char*)LDS + cur + aoff[mi][ks]);
#pragma unroll
    for (int ni = 0; ni < 4; ++ni)
#pragma unroll
      for (int ks = 0; ks < 2; ++ks)
        bR[ni][ks] = *(const bf16x8*)((const char*)LDS + cur + boff[ni][ks]);
    if (mode == 2) {
      uint32_t stg = cur + 2 * LDSB;
      if (stg >= 3 * LDSB) stg -= 3 * LDSB;
      stage_tile(kt + 2, stg);
    }
    __builtin_amdgcn_sched_barrier(0);
    __builtin_amdgcn_s_setprio(1);
#pragma unroll
    for (int ks = 0; ks < 2; ++ks)
#pragma unroll
      for (int mi = 0; mi < 4; ++mi)
#pragma unroll
        for (int ni = 0; ni < 4; ++ni)
          acc[mi][ni] = __builtin_amdgcn_mfma_f32_16x16x32_bf16(aR[mi][ks], bR[ni][ks], acc[mi][ni], 0, 0, 0);
    __builtin_amdgcn_s_setprio(0);
    if (mode == 2) {
      asm volatile("s_waitcnt vmcnt(6)" ::: "memory");
    } else if (mode == 1) {
      asm volatile("s_waitcnt vmcnt(0)" ::: "memory");
    }
    if (mode != 0) {
      __builtin_amdgcn_s_barrier();
      __builtin_amdgcn_sched_barrier(0);
    }
  };

  // prologue: stage tiles 0,1 -> bufs 0,1 (12 in flight), wait oldest 6.
  stage_tile(0, 0);
  stage_tile(1, LDSB);
  asm volatile("s_waitcnt vmcnt(6)" ::: "memory");
  __builtin_amdgcn_s_barrier();
  __builtin_amdgcn_sched_barrier(0);

  uint32_t cur = 0;
#pragma unroll 1
  for (int kt = 0; kt < NT - 2; ++kt) {
    tile_body(kt, cur, 2);
    cur += LDSB; if (cur == 3 * LDSB) cur = 0;
  }
  tile_body(NT - 2, cur, 1);
  cur += LDSB; if (cur == 3 * LDSB) cur = 0;
  tile_body(NT - 1, cur, 0);

  // epilogue: Out = relu(HW - dinv[row] * acc), direct per-wave (full K owned).
  int bq = n0 >> 8;
#pragma unroll
  for (int mi = 0; mi < 4; ++mi) {
    int row = m0 + wm * 64 + mi * 16 + q * 4;
    float di[4];
#pragma unroll
    for (int rr = 0; rr < 4; ++rr) di[rr] = dinv[row + rr];
#pragma unroll
    for (int ni = 0; ni < 4; ++ni) {
      int col = n0 + wn * 64 + ni * 16 + r16;
      int o = col & 255;
#pragma unroll
      for (int rr = 0; rr < 4; ++rr) {
        size_t oi = ((size_t)bq * N_NODES + (row + rr)) * F_DIM + o;
        float u = bf2f(HWb[oi]) - di[rr] * acc[mi][ni][rr];
        Out[oi] = u > 0.f ? u : 0.f;
      }
    }
  }
}

extern "C" void kernel_launch(void* const* d_in, const int* in_sizes, int n_in,
                              void* d_out, int out_size, void* d_ws, size_t ws_size,
                              hipStream_t stream) {
  (void)in_sizes; (void)n_in; (void)out_size; (void)ws_size;
  const float* H = (const float*)d_in[0];
  const float* W = (const float*)d_in[1];
  const float* A = (const float*)d_in[2];
  float* out = (float*)d_out;

  char* ws = (char*)d_ws;
  size_t off = 0;
  auto alloc = [&](size_t bytes) {
    char* p = ws + off;
    off += (bytes + 255) & ~(size_t)255;
    return p;
  };
  float*          Dd   = (float*)alloc((size_t)N_NODES * 4);
  float*          dinv = (float*)alloc((size_t)N_NODES * 4);
  unsigned short* Sb   = (unsigned short*)alloc((size_t)N_NODES * N_NODES * 2);        // 32 MB
  unsigned short* HWb  = (unsigned short*)alloc((size_t)BATCH * N_NODES * F_DIM * 2);  // 16 MB
  unsigned short* Gt   = (unsigned short*)alloc((size_t)BATCH * F_DIM * N_NODES * 2);  // 16 MB
  unsigned short* Wt   = (unsigned short*)alloc((size_t)F_DIM * F_DIM * 2);
  unsigned short* Hb   = (unsigned short*)alloc((size_t)BATCH * N_NODES * F_DIM * 2);  // 16 MB

  hipMemsetAsync(Dd, 0, N_NODES * 4, stream);
  k_pre<<<dim3(64, 64), 256, 0, stream>>>(A, Sb, Dd, (const float4*)H, (ushort4*)Hb, W, Wt);
  k_dinv<<<16, 256, 0, stream>>>(Dd, dinv);
  k_gemm1<<<dim3(2, 256), 256, 0, stream>>>(Hb, Wt, dinv, HWb, Gt);
  k_gemm2<<<dim3(256), 512, 0, stream>>>(Sb, Gt, HWb, dinv, out);
}